// Round 7
// baseline (1385.143 us; speedup 1.0000x reference)
//
#include <hip/hip_runtime.h>
#include <cmath>

// SSIM fused kernel, wave-autonomous version (R6 + occupancy fix).
// Each wave (64 lanes) owns a 64-col x 32-row output tile of one plane and a
// PRIVATE 74-slot LDS row buffer (cols c0-5 .. c0+68). Staging and horizontal
// conv are wave-synchronous (HW DS pipe is in-order per wave); compiler
// reordering across the per-lane LDS aliasing is blocked by asm memory
// fences (R5->R6 fix, absmax 0). No __syncthreads anywhere.
//
// R6 lesson: amdgpu_waves_per_eu(1) let the allocator balloon to 232 VGPRs
// -> 11% occupancy -> per-row load latency (LLC ~200-500cyc) fully exposed,
// 199us. This version: waves_per_eu(4) caps VGPRs at 128 (>=4 waves/SIMD)
// so TLP hides the row-load latency. Live state ~75 floats; fits.

#define IMG_H 512
#define IMG_W 512
#define STRIPE 32
#define NSTR 16
#define NPLANES 48
#define NWAVES (NPLANES * NSTR * 8)    // 6144 waves, 64 cols each
#define NBLOCKS (NWAVES / 4)           // 1536 blocks of 256 threads
#define SSIM_C1 (0.01f * 0.01f)
#define SSIM_C2 (0.03f * 0.03f)

#define WAVE_MEM_FENCE() asm volatile("" ::: "memory")

struct W11 { float w[11]; };

__attribute__((amdgpu_flat_work_group_size(256, 256), amdgpu_waves_per_eu(4)))
__global__ void ssim_main(const float* __restrict__ img1,
                          const float* __restrict__ img2,
                          float* __restrict__ waveSums, W11 wv) {
    __shared__ float2 tb[4][80];   // per-wave private; slots 0..73 used

    const int tid = threadIdx.x;
    const int wia = tid >> 6;      // wave in block
    const int l   = tid & 63;
    const int bid = blockIdx.x;
    const int plane  = bid >> 5;          // 48 planes
    const int rem    = bid & 31;
    const int stripe = rem >> 1;          // 16 row-stripes
    const int half   = rem & 1;           // which 256-col half
    const int c0 = half * 256 + wia * 64; // wave's first column
    const int y0 = stripe * STRIPE;
    const int col = c0 + l;               // own column (always < 512)

    const float* __restrict__ p1 = img1 + (size_t)plane * (IMG_H * IMG_W);
    const float* __restrict__ p2 = img2 + (size_t)plane * (IMG_H * IMG_W);

    float2* buf = tb[wia];

    // halo: lanes 0..4 -> cols c0-5..c0-1 (slots 0..4),
    //       lanes 5..9 -> cols c0+64..c0+68 (slots 69..73)
    const bool hlane  = (l < 10);
    const int  hraw   = (l < 5) ? (c0 - 5 + l) : (c0 + 59 + l);
    const bool hvalid = hlane && (hraw >= 0) && (hraw < IMG_W);
    const int  hcol   = hvalid ? hraw : 0;       // clamped, masked later
    const int  hslot  = (l < 5) ? l : (l + 64);  // 0..4 / 69..73

    float rA[11], rB[11], rS[11], rP[11];  // vertical ring, static-indexed
    float acc = 0.f;
    float pa = 0.f, pb = 0.f, hpa = 0.f, hpb = 0.f;

#define LOAD_ROW(RI) do {                                                   \
    const int ri_ = (RI);                                                   \
    if (ri_ >= 0 && ri_ < IMG_H) {      /* wave-uniform branch */           \
        const size_t off_ = (size_t)ri_ * IMG_W;                            \
        pa = p1[off_ + col]; pb = p2[off_ + col];                           \
        if (hlane) {                                                        \
            const float ta_ = p1[off_ + hcol], tb_ = p2[off_ + hcol];       \
            hpa = hvalid ? ta_ : 0.f; hpb = hvalid ? tb_ : 0.f;             \
        }                                                                   \
    } else { pa = 0.f; pb = 0.f; hpa = 0.f; hpb = 0.f; }                    \
} while (0)

// Stage current row (regs -> LDS), compute own-tap (k=5) from regs, start
// the next row's loads, then do the remaining 10 horizontal taps from LDS.
// Fences: pre-write fence blocks this row's writes from hoisting above the
// PREVIOUS row's ds_reads (WAR); post-write fence blocks this row's ds_reads
// from hoisting above the writes (RAW). HW DS pipe is in-order per wave.
#define STAGE_AND_H(PHASE, RINEXT) do {                                     \
    WAVE_MEM_FENCE();                                                       \
    buf[l + 5] = make_float2(pa, pb);                                       \
    if (hlane) buf[hslot] = make_float2(hpa, hpb);                          \
    WAVE_MEM_FENCE();                                                       \
    float h0_, h1_, h2_, h3_;                                               \
    { const float w_ = wv.w[5];                                             \
      const float sq_ = fmaf(pb, pb, pa * pa);                              \
      const float pr_ = pa * pb;                                            \
      h0_ = w_ * pa; h1_ = w_ * pb; h2_ = w_ * sq_; h3_ = w_ * pr_; }       \
    LOAD_ROW(RINEXT);                                                       \
    _Pragma("unroll")                                                       \
    for (int k_ = 0; k_ < 11; ++k_) {                                       \
        if (k_ != 5) {                                                      \
            const float2 t_ = buf[l + k_];   /* ds_read_b64 */              \
            const float w_ = wv.w[k_];                                      \
            const float sq_ = fmaf(t_.y, t_.y, t_.x * t_.x);                \
            const float pr_ = t_.x * t_.y;                                  \
            h0_ = fmaf(w_, t_.x, h0_); h1_ = fmaf(w_, t_.y, h1_);           \
            h2_ = fmaf(w_, sq_, h2_);  h3_ = fmaf(w_, pr_, h3_);            \
        }                                                                   \
    }                                                                       \
    rA[PHASE] = h0_; rB[PHASE] = h1_;                                       \
    rS[PHASE] = h2_; rP[PHASE] = h3_;                                       \
} while (0)

    LOAD_ROW(y0 - 5);

    // prologue: fill ring phases 0..9 (input rows y0-5 .. y0+4)
#pragma unroll
    for (int i = 0; i < 10; ++i) {
        STAGE_AND_H(i, y0 - 4 + i);
    }

    // main: 32 output rows; phase arithmetic static since outer*11 % 11 == 0
#pragma unroll 1
    for (int outer = 0; outer < 3; ++outer) {
#pragma unroll
        for (int jj = 0; jj < 11; ++jj) {
            const int m = outer * 11 + jj;
            if (m < 32) {                        // wave-uniform guard
                STAGE_AND_H((10 + jj) % 11, (m < 31) ? (y0 + 6 + m) : -1);
                float vA = 0.f, vB = 0.f, vS = 0.f, vP = 0.f;
#pragma unroll
                for (int k = 0; k < 11; ++k) {
                    const int s = (jj + k) % 11; // static per (jj,k)
                    const float w = wv.w[k];
                    vA = fmaf(w, rA[s], vA);
                    vB = fmaf(w, rB[s], vB);
                    vS = fmaf(w, rS[s], vS);
                    vP = fmaf(w, rP[s], vP);
                }
                const float mu11 = vA * vA;
                const float mu22 = vB * vB;
                const float mu12 = vA * vB;
                const float num = fmaf(2.f, mu12, SSIM_C1) *
                                  fmaf(2.f, vP - mu12, SSIM_C2);
                const float d1  = mu11 + mu22;
                const float den = (d1 + SSIM_C1) * ((vS - d1) + SSIM_C2);
                acc = fmaf(num, __builtin_amdgcn_rcpf(den), acc);
            }
        }
    }

#undef LOAD_ROW
#undef STAGE_AND_H

    // wave-level reduction only; one partial per wave (no cross-wave sync)
#pragma unroll
    for (int off = 32; off >= 1; off >>= 1)
        acc += __shfl_down(acc, off, 64);
    if (l == 0) waveSums[bid * 4 + wia] = acc;
}

__global__ void ssim_reduce(const float* __restrict__ ws,
                            float* __restrict__ out) {
    __shared__ double red[16];
    const int t = threadIdx.x;  // 1024 threads
    double a = 0.0;
    for (int i = t; i < NWAVES; i += 1024) a += (double)ws[i];
#pragma unroll
    for (int off = 32; off >= 1; off >>= 1)
        a += __shfl_down(a, off, 64);
    const int wv_ = t >> 6, lane = t & 63;
    if (lane == 0) red[wv_] = a;
    __syncthreads();
    if (t == 0) {
        double s = 0.0;
#pragma unroll
        for (int k = 0; k < 16; ++k) s += red[k];
        out[0] = (float)(s / ((double)NPLANES * IMG_H * IMG_W));
    }
}

extern "C" void kernel_launch(void* const* d_in, const int* in_sizes, int n_in,
                              void* d_out, int out_size, void* d_ws, size_t ws_size,
                              hipStream_t stream) {
    const float* img1 = (const float*)d_in[0];
    const float* img2 = (const float*)d_in[1];
    float* out = (float*)d_out;
    float* wsums = (float*)d_ws;   // 6144 floats = 24 KB scratch

    // Gaussian weights, faithful to reference: center 5.5, sigma 1.5
    W11 wv;
    double g[11], s = 0.0;
    for (int i = 0; i < 11; ++i) {
        const double d = (double)i - 5.5;
        g[i] = exp(-(d * d) / (2.0 * 1.5 * 1.5));
        s += g[i];
    }
    for (int i = 0; i < 11; ++i) wv.w[i] = (float)(g[i] / s);

    ssim_main<<<NBLOCKS, 256, 0, stream>>>(img1, img2, wsums, wv);
    ssim_reduce<<<1, 1024, 0, stream>>>(wsums, out);
}

// Round 8
// 164.838 us; speedup vs baseline: 8.4030x; 8.4030x over previous
//
#include <hip/hip_runtime.h>
#include <cmath>

// SSIM fused kernel — R3 structure + 2 rows per barrier (double-buffered).
// Separable 11-tap Gaussian. Horizontal conv via float2-interleaved LDS rows;
// vertical via per-thread register ring of FOUR quantities:
// conv(a), conv(b), conv(a^2+b^2), conv(ab).
// One block = one (plane, 32-row stripe); 512 threads = 1 column each.
// 21 row-PAIRS per block -> 21 barriers (R3 had 42). 4 global loads in
// flight per barrier. Ring phases static: pair p cycles (2p)%11,(2p+1)%11.
//
// Register-allocation notes (hard-won): __launch_bounds__(512,2) is the only
// config that behaves: VGPR~52-64 + ring in AGPRs, no scratch. waves_per_eu(1)
// ballooned to 232 VGPR (R6, 199us); waves_per_eu(4) spilled the ring to
// scratch (R7: WRITE_SIZE 2.9GB, 1322us). Do not touch the attributes.

#define IMG_H 512
#define IMG_W 512
#define STRIPE 32
#define NSTR (IMG_H / STRIPE)      // 16
#define NPLANES 48                 // 16*3
#define NBLOCKS (NPLANES * NSTR)   // 768
#define SSIM_C1 (0.01f * 0.01f)
#define SSIM_C2 (0.03f * 0.03f)

struct W11 { float w[11]; };

__launch_bounds__(512, 2)
__global__ void ssim_main(const float* __restrict__ img1,
                          const float* __restrict__ img2,
                          float* __restrict__ blockSums, W11 wv) {
    // [buf][rowparity][col]; cols 0..521 used (5 halo each side), pad 528
    __shared__ float2 tb[2][2][528];
    __shared__ float red[8];

    const int x = threadIdx.x;            // 0..511, one output column
    const int bid = blockIdx.x;
    const int plane = bid >> 4;           // /NSTR
    const int stripe = bid & (NSTR - 1);
    const int y0 = stripe * STRIPE;
    const size_t base = (size_t)plane * (IMG_H * IMG_W);
    const float* __restrict__ p1 = img1 + base;
    const float* __restrict__ p2 = img2 + base;

    // zero halo pads once (cols 0..4 and 517..521, all 4 row-slots)
    if (x < 10) {
        const int col = (x < 5) ? x : (x + 512);
        tb[0][0][col] = make_float2(0.f, 0.f);
        tb[0][1][col] = make_float2(0.f, 0.f);
        tb[1][0][col] = make_float2(0.f, 0.f);
        tb[1][1][col] = make_float2(0.f, 0.f);
    }

    float rA[11], rB[11], rS[11], rP[11];  // vertical ring, static-indexed
    float acc = 0.f;

    // prefetched pair of rows (registers)
    float pa0 = 0.f, pb0 = 0.f, pa1 = 0.f, pb1 = 0.f;

#define LOAD2(RI, PA, PB) do {                                              \
    const int r_ = (RI);                                                    \
    if (r_ >= 0 && r_ < IMG_H) {   /* block-uniform branch */               \
        const size_t o_ = (size_t)r_ * IMG_W + x;                           \
        PA = p1[o_]; PB = p2[o_];                                           \
    } else { PA = 0.f; PB = 0.f; }                                          \
} while (0)

// horizontal 11-tap conv of one staged row -> ring phase PH
#define HCONV(BUF, PAR, PH) do {                                            \
    float h0_ = 0.f, h1_ = 0.f, h2_ = 0.f, h3_ = 0.f;                       \
    _Pragma("unroll")                                                       \
    for (int k_ = 0; k_ < 11; ++k_) {                                       \
        const float2 t_ = tb[BUF][PAR][x + k_];   /* ds_read_b64 */         \
        const float w_ = wv.w[k_];                                          \
        const float sq_ = fmaf(t_.y, t_.y, t_.x * t_.x);                    \
        const float pr_ = t_.x * t_.y;                                      \
        h0_ = fmaf(w_, t_.x, h0_); h1_ = fmaf(w_, t_.y, h1_);               \
        h2_ = fmaf(w_, sq_, h2_);  h3_ = fmaf(w_, pr_, h3_);                \
    }                                                                       \
    rA[PH] = h0_; rB[PH] = h1_; rS[PH] = h2_; rP[PH] = h3_;                 \
} while (0)

// vertical 11-tap conv (ring base VB) + SSIM accumulate
#define VCONV_SSIM(VB) do {                                                 \
    float vA_ = 0.f, vB_ = 0.f, vS_ = 0.f, vP_ = 0.f;                       \
    _Pragma("unroll")                                                       \
    for (int k_ = 0; k_ < 11; ++k_) {                                       \
        const int s_ = ((VB) + k_) % 11;       /* static per (VB,k) */      \
        const float w_ = wv.w[k_];                                          \
        vA_ = fmaf(w_, rA[s_], vA_); vB_ = fmaf(w_, rB[s_], vB_);           \
        vS_ = fmaf(w_, rS[s_], vS_); vP_ = fmaf(w_, rP[s_], vP_);           \
    }                                                                       \
    const float mu11_ = vA_ * vA_;                                          \
    const float mu22_ = vB_ * vB_;                                          \
    const float mu12_ = vA_ * vB_;                                          \
    const float num_ = fmaf(2.f, mu12_, SSIM_C1) *                          \
                       fmaf(2.f, vP_ - mu12_, SSIM_C2);                     \
    const float d1_  = mu11_ + mu22_;                                       \
    const float den_ = (d1_ + SSIM_C1) * ((vS_ - d1_) + SSIM_C2);           \
    acc = fmaf(num_, __builtin_amdgcn_rcpf(den_), acc);                     \
} while (0)

    // prefetch pair q=0: rows y0-5, y0-4
    LOAD2(y0 - 5, pa0, pb0);
    LOAD2(y0 - 4, pa1, pb1);

    int buf = 0;
#pragma unroll 1
    for (int outer = 0; outer < 2; ++outer) {
#pragma unroll
        for (int p = 0; p < 11; ++p) {
            const int q = outer * 11 + p;     // pair index 0..21
            if (q < 21) {                     // block-uniform guard
                // stage prefetched pair into LDS
                tb[buf][0][x + 5] = make_float2(pa0, pb0);
                tb[buf][1][x + 5] = make_float2(pa1, pb1);
                // prefetch next pair (rows y0-5+2q+2, +3)
                if (q < 20) {
                    LOAD2(y0 - 3 + 2 * q, pa0, pb0);
                    LOAD2(y0 - 2 + 2 * q, pa1, pb1);
                }
                __syncthreads();
                // phases: row i0=2q -> (2p)%11 ; i1=2q+1 -> (2p+1)%11
                HCONV(buf, 0, (2 * p) % 11);
                HCONV(buf, 1, (2 * p + 1) % 11);
                // outputs active from q>=5 (rows 10,11 -> out 0,1)
                if (q >= 5) {
                    VCONV_SSIM((2 * p + 1) % 11);  // out row 2q-10
                    VCONV_SSIM((2 * p + 2) % 11);  // out row 2q-9
                }
                buf ^= 1;
            }
        }
    }

#undef LOAD2
#undef HCONV
#undef VCONV_SSIM

    // block reduction: wave shuffle, then 8 wave-sums via LDS
#pragma unroll
    for (int off = 32; off >= 1; off >>= 1)
        acc += __shfl_down(acc, off, 64);
    const int wave = x >> 6, lane = x & 63;
    if (lane == 0) red[wave] = acc;
    __syncthreads();
    if (x == 0) {
        float s = 0.f;
#pragma unroll
        for (int k = 0; k < 8; ++k) s += red[k];
        blockSums[bid] = s;
    }
}

__global__ void ssim_reduce(const float* __restrict__ bs,
                            float* __restrict__ out) {
    __shared__ double red[4];
    const int t = threadIdx.x;  // 256 threads
    double a = 0.0;
    for (int idx = t; idx < NBLOCKS; idx += 256) a += (double)bs[idx];
#pragma unroll
    for (int off = 32; off >= 1; off >>= 1)
        a += __shfl_down(a, off, 64);
    const int wave = t >> 6, lane = t & 63;
    if (lane == 0) red[wave] = a;
    __syncthreads();
    if (t == 0) {
        const double s = red[0] + red[1] + red[2] + red[3];
        out[0] = (float)(s / (double)((double)NPLANES * IMG_H * IMG_W));
    }
}

extern "C" void kernel_launch(void* const* d_in, const int* in_sizes, int n_in,
                              void* d_out, int out_size, void* d_ws, size_t ws_size,
                              hipStream_t stream) {
    const float* img1 = (const float*)d_in[0];
    const float* img2 = (const float*)d_in[1];
    float* out = (float*)d_out;
    float* bs = (float*)d_ws;   // 768 floats of scratch

    // Gaussian weights, faithful to reference: center 5.5, sigma 1.5
    W11 wv;
    double g[11], s = 0.0;
    for (int i = 0; i < 11; ++i) {
        const double d = (double)i - 5.5;
        g[i] = exp(-(d * d) / (2.0 * 1.5 * 1.5));
        s += g[i];
    }
    for (int i = 0; i < 11; ++i) wv.w[i] = (float)(g[i] / s);

    ssim_main<<<NBLOCKS, 512, 0, stream>>>(img1, img2, bs, wv);
    ssim_reduce<<<1, 256, 0, stream>>>(bs, out);
}